// Round 3
// baseline (149.594 us; speedup 1.0000x reference)
//
#include <hip/hip_runtime.h>
#include <math.h>

#define HH 496
#define WW 496
#define HWSZ (HH*WW)
#define NW 31
#define NWIN (NW*NW)   // 961
#define NB 16          // conv grid 16x16, 32x32-pixel tiles
#define NCONVB (NB*NB) // 256 conv blocks
#define PARTSTRIDE 1024

typedef float nf4 __attribute__((ext_vector_type(4)));  // native vec for nontemporal builtin
typedef float nf2 __attribute__((ext_vector_type(2)));

__constant__ float c_thetas[8] = {
    0.39269908169872414f, 0.7853981633974483f, 1.1780972450961724f,
    1.5707963267948966f,  1.9634954084936207f, 2.356194490192345f,
    2.748893571891069f,   3.141592653589793f};

// ---- conv: 4 pixels/thread (2x2). 96 named accumulators (q/r/s/t x 24) --
// arrays get demoted to scratch, names stay in VGPRs. One filter LDS read
// feeds 4 FMAs -> per-CU LDS filter traffic drops 4x vs 1 px/thread. ----

// one filter value -> 4 pixel FMAs. fb is a scope variable (flds offset).
#define F4(N, PA, PB, PC, PD) { float w = flds[fb + (N)]; \
    q##N = fmaf(PA, w, q##N); r##N = fmaf(PB, w, r##N); \
    s##N = fmaf(PC, w, s##N); t##N = fmaf(PD, w, t##N); }

#define STEP(K, PA, PB, PC, PD) { const int fb = cgo + (K)*72; \
    F4(0,PA,PB,PC,PD)  F4(1,PA,PB,PC,PD)  F4(2,PA,PB,PC,PD)  F4(3,PA,PB,PC,PD)  \
    F4(4,PA,PB,PC,PD)  F4(5,PA,PB,PC,PD)  F4(6,PA,PB,PC,PD)  F4(7,PA,PB,PC,PD)  \
    F4(8,PA,PB,PC,PD)  F4(9,PA,PB,PC,PD)  F4(10,PA,PB,PC,PD) F4(11,PA,PB,PC,PD) \
    F4(12,PA,PB,PC,PD) F4(13,PA,PB,PC,PD) F4(14,PA,PB,PC,PD) F4(15,PA,PB,PC,PD) \
    F4(16,PA,PB,PC,PD) F4(17,PA,PB,PC,PD) F4(18,PA,PB,PC,PD) F4(19,PA,PB,PC,PD) \
    F4(20,PA,PB,PC,PD) F4(21,PA,PB,PC,PD) F4(22,PA,PB,PC,PD) F4(23,PA,PB,PC,PD) }

// tap (dy,dx): px(0,0)->p{dy}{dx}, px(0,1)->p{dy}{dx+1}, px(1,0)->p{dy+1}{dx}, px(1,1)->p{dy+1}{dx+1}
#define ALLSTEPS \
    STEP(0,  p00,p01,p10,p11) STEP(1,  p01,p02,p11,p12) STEP(2,  p02,p03,p12,p13) \
    STEP(3,  p03,p04,p13,p14) STEP(4,  p04,p05,p14,p15) \
    STEP(5,  p10,p11,p20,p21) STEP(6,  p11,p12,p21,p22) STEP(7,  p12,p13,p22,p23) \
    STEP(8,  p13,p14,p23,p24) STEP(9,  p14,p15,p24,p25) \
    STEP(10, p20,p21,p30,p31) STEP(11, p21,p22,p31,p32) STEP(12, p22,p23,p32,p33) \
    STEP(13, p23,p24,p33,p34) STEP(14, p24,p25,p34,p35) \
    STEP(15, p30,p31,p40,p41) STEP(16, p31,p32,p41,p42) STEP(17, p32,p33,p42,p43) \
    STEP(18, p33,p34,p43,p44) STEP(19, p34,p35,p44,p45) \
    STEP(20, p40,p41,p50,p51) STEP(21, p41,p42,p51,p52) STEP(22, p42,p43,p52,p53) \
    STEP(23, p43,p44,p53,p54) STEP(24, p44,p45,p54,p55)

#define MAX8(A,B,C,D,E,F,G,H) \
    fmaxf(fmaxf(fmaxf(A,B),fmaxf(C,D)),fmaxf(fmaxf(E,F),fmaxf(G,H)))

#define RED(CC, MV) { \
        float s_ = MV; \
        s_ += __shfl_down(s_, 32, 64); s_ += __shfl_down(s_, 16, 64); \
        s_ += __shfl_down(s_,  8, 64); s_ += __shfl_down(s_,  4, 64); \
        s_ += __shfl_down(s_,  2, 64); s_ += __shfl_down(s_,  1, 64); \
        if ((tid & 63) == 0) red[tid >> 6][CC] = s_; }

__global__ __launch_bounds__(256, 1) void conv_kernel(
    const float* __restrict__ img,
    const float* __restrict__ sigmas, const float* __restrict__ lambdas,
    float* __restrict__ out, float* __restrict__ partial) {
    __shared__ float tile[36 * 36];
    __shared__ __align__(16) float flds[1800];
    __shared__ float red[4][9];
    int tid = threadIdx.x;
    int tx = tid & 15, ty = tid >> 4;
    int bx = blockIdx.x, by = blockIdx.y;
    int x0 = bx * 32, y0 = by * 32;

    // stage 36x36 image tile (halo 2); global loads issue first, bank math overlaps latency
    for (int i = tid; i < 1296; i += 256) {
        int tY = i / 36, tX = i % 36;
        int gy = y0 + tY - 2, gx = x0 + tX - 2;
        float v = 0.0f;
        if (gy >= 0 && gy < HH && gx >= 0 && gx < WW) v = img[gy * WW + gx];
        tile[i] = v;
    }
    // compute Gabor bank into LDS -- bit-identical math to the original bank_kernel
    for (int idx = tid; idx < 1800; idx += 256) {
        int f = idx / 25, k = idx % 25;
        int dy = k / 5, dx = k % 5;
        int s = f / 24, rem = f % 24, l = rem / 8, t = rem % 8;
        float sig = sigmas[s], lam = lambdas[l], th = c_thetas[t];
        float yy = (float)dy - 2.0f, xx = (float)dx - 2.0f;
        float st = sinf(th), ct = cosf(th);
        float yt = -xx * st + yy * ct;
        float xt =  xx * ct + yy * st;
        float sx2 = sig * sig;          // sigma_x = sig
        float sy2 = 4.0f * sig * sig;   // sigma_y = sig/0.5
        float g = expf(-0.5f * (xt * xt / sx2 + yt * yt / sy2)) *
                  cosf(6.28318530717958647692f * xt / lam + 1.5707963267948966f);
        flds[k * 72 + f] = g;           // transposed layout: filt[k][f]
    }
    __syncthreads();

    // 6x6 pixel window in named registers (18 ds_read_b64 after merging),
    // shared by the 2x2 output pixels across all 3 channel groups.
    int rb = (2 * ty) * 36 + 2 * tx;
    float p00=tile[rb+  0], p01=tile[rb+  1], p02=tile[rb+  2], p03=tile[rb+  3], p04=tile[rb+  4], p05=tile[rb+  5];
    float p10=tile[rb+ 36], p11=tile[rb+ 37], p12=tile[rb+ 38], p13=tile[rb+ 39], p14=tile[rb+ 40], p15=tile[rb+ 41];
    float p20=tile[rb+ 72], p21=tile[rb+ 73], p22=tile[rb+ 74], p23=tile[rb+ 75], p24=tile[rb+ 76], p25=tile[rb+ 77];
    float p30=tile[rb+108], p31=tile[rb+109], p32=tile[rb+110], p33=tile[rb+111], p34=tile[rb+112], p35=tile[rb+113];
    float p40=tile[rb+144], p41=tile[rb+145], p42=tile[rb+146], p43=tile[rb+147], p44=tile[rb+148], p45=tile[rb+149];
    float p50=tile[rb+180], p51=tile[rb+181], p52=tile[rb+182], p53=tile[rb+183], p54=tile[rb+184], p55=tile[rb+185];

    int xx0 = x0 + 2 * tx, yy0 = y0 + 2 * ty;
    // xx0,yy0 even and 496 even: xx0<496 => xx0+1<496 -- one predicate covers all 4 px
    bool inb = (xx0 < WW) && (yy0 < HH);

#pragma unroll 1
    for (int cg = 0; cg < 3; ++cg) {
        const int cgo = cg * 24;
        float q0=0,q1=0,q2=0,q3=0,q4=0,q5=0,q6=0,q7=0,q8=0,q9=0,q10=0,q11=0,
              q12=0,q13=0,q14=0,q15=0,q16=0,q17=0,q18=0,q19=0,q20=0,q21=0,q22=0,q23=0;
        float r0=0,r1=0,r2=0,r3=0,r4=0,r5=0,r6=0,r7=0,r8=0,r9=0,r10=0,r11=0,
              r12=0,r13=0,r14=0,r15=0,r16=0,r17=0,r18=0,r19=0,r20=0,r21=0,r22=0,r23=0;
        float s0=0,s1=0,s2=0,s3=0,s4=0,s5=0,s6=0,s7=0,s8=0,s9=0,s10=0,s11=0,
              s12=0,s13=0,s14=0,s15=0,s16=0,s17=0,s18=0,s19=0,s20=0,s21=0,s22=0,s23=0;
        float t0=0,t1=0,t2=0,t3=0,t4=0,t5=0,t6=0,t7=0,t8=0,t9=0,t10=0,t11=0,
              t12=0,t13=0,t14=0,t15=0,t16=0,t17=0,t18=0,t19=0,t20=0,t21=0,t22=0,t23=0;

        ALLSTEPS

        // channel maxes for the 4 pixels (identical fmaxf tree to before, per px)
        float mq0=MAX8(q0,q1,q2,q3,q4,q5,q6,q7),     mq1=MAX8(q8,q9,q10,q11,q12,q13,q14,q15),
              mq2=MAX8(q16,q17,q18,q19,q20,q21,q22,q23);
        float mr0=MAX8(r0,r1,r2,r3,r4,r5,r6,r7),     mr1=MAX8(r8,r9,r10,r11,r12,r13,r14,r15),
              mr2=MAX8(r16,r17,r18,r19,r20,r21,r22,r23);
        float ms0=MAX8(s0,s1,s2,s3,s4,s5,s6,s7),     ms1=MAX8(s8,s9,s10,s11,s12,s13,s14,s15),
              ms2=MAX8(s16,s17,s18,s19,s20,s21,s22,s23);
        float mt0=MAX8(t0,t1,t2,t3,t4,t5,t6,t7),     mt1=MAX8(t8,t9,t10,t11,t12,t13,t14,t15),
              mt2=MAX8(t16,t17,t18,t19,t20,t21,t22,t23);

#define EPI(J, MQ, MR, MS, MT) { \
            int ch = cg * 3 + (J); \
            if (inb) { \
                *(nf2*)(out + (size_t)ch * HWSZ + (size_t)yy0 * WW + xx0)       = (nf2){MQ, MR}; \
                *(nf2*)(out + (size_t)ch * HWSZ + (size_t)(yy0 + 1) * WW + xx0) = (nf2){MS, MT}; \
            } \
            float sm = inb ? (MQ + MR + MS + MT) : 0.0f; \
            RED(ch, sm) }
        EPI(0, mq0, mr0, ms0, mt0)
        EPI(1, mq1, mr1, ms1, mt1)
        EPI(2, mq2, mr2, ms2, mt2)
#undef EPI
    }

    __syncthreads();
    if (tid < 9) {
        int bid = by * NB + bx;
        partial[tid * PARTSTRIDE + bid] =
            red[0][tid] + red[1][tid] + red[2][tid] + red[3][tid];
    }
}

// ---- Kernel 2: mean-reduce preamble + per-window validity + patch copy (valid ~3.5%) ----
__global__ __launch_bounds__(256) void patch_kernel(
    const float* __restrict__ out, const float* __restrict__ partial,
    float* __restrict__ dst) {
    int w = blockIdx.x;
    int r = w / NW, cl = w % NW;
    int tid = threadIdx.x;
    __shared__ float sm5[9];
    __shared__ int lds_and[4];
    __shared__ int lds_or[4];

    // Preamble: reduce 256 per-block conv partials -> 5*mean per channel (all L2-hits)
    {
        int lane = tid & 63, wid = tid >> 6;
        for (int c = wid; c < 9; c += 4) {
            float s = 0.0f;
            for (int b = lane; b < NCONVB; b += 64) s += partial[c * PARTSTRIDE + b];
            s += __shfl_down(s, 32, 64); s += __shfl_down(s, 16, 64);
            s += __shfl_down(s,  8, 64); s += __shfl_down(s,  4, 64);
            s += __shfl_down(s,  2, 64); s += __shfl_down(s,  1, 64);
            if (lane == 0) sm5[c] = s * (5.0f / (float)HWSZ);
        }
    }
    __syncthreads();

    // Stage 1: per-channel "argmax of thresholded window == 128" bit, AND over threads
    int wy = tid >> 4, wx = tid & 15;
    int rowbase = (r * 16 + wy) * WW + cl * 16 + wx;
    int cbase   = (r * 16 + 8) * WW + cl * 16;       // flat idx 128 = (8,0)
    int okmask = 0;
#pragma unroll
    for (int c = 0; c < 9; c++) {
        float m5 = sm5[c];
        float v  = out[c * HWSZ + rowbase];
        float vc = out[c * HWSZ + cbase];
        float thr  = (v  > m5) ? v  : 0.0f;
        float thrc = (vc > m5) ? vc : 0.0f;
        // first-occurrence argmax: earlier strictly less, later (incl. center) <=
        bool ok = (tid < 128) ? (thr < thrc) : (thr <= thrc);
        okmask |= (ok ? 1 : 0) << c;
    }
#pragma unroll
    for (int off = 1; off < 64; off <<= 1) okmask &= __shfl_xor(okmask, off, 64);
    if ((tid & 63) == 0) lds_and[tid >> 6] = okmask;
    __syncthreads();

    int am = lds_and[0] & lds_and[1] & lds_and[2] & lds_and[3];

    int i = tid >> 3;            // patch row 0..31
    int jg = (tid & 7) << 2;     // patch col group 0,4,...,28
    size_t dbase = (size_t)w * 1024 + i * 32 + jg;

    if (am == 0) {
        // no channel has center-argmax: entire 9-channel patch set is zero.
        // must still store (dst is poisoned), but skip all patch reads.
        nf4 z = (nf4){0.f, 0.f, 0.f, 0.f};
#pragma unroll
        for (int c = 0; c < 9; c++)
            __builtin_nontemporal_store(z, (nf4*)(dst + (size_t)c * NWIN * 1024 + dbase));
        return;
    }

    // Stage 2 (valid windows only): one float4 per (thread, channel); nz bitmask
    int row = r * 16 + i - 8;
    int col = cl * 16 + jg - 8;
    // 4-aligned col groups never straddle the [0,496) edge (496 % 4 == 0)
    bool inb = (row >= 0 && row < HH && col >= 0 && col + 3 < WW);
    size_t pbase = (size_t)row * WW + col;
    int nzmask = 0;
    nf4 p0, p1, p2, p3, p4, p5, p6, p7, p8;
#define LOADP(C, V) { \
        V = (nf4){0.f, 0.f, 0.f, 0.f}; \
        if (inb) V = *(const nf4*)(out + (size_t)(C) * HWSZ + pbase); \
        if (V.x != 0.f || V.y != 0.f || V.z != 0.f || V.w != 0.f) nzmask |= 1 << (C); }
    LOADP(0,p0) LOADP(1,p1) LOADP(2,p2) LOADP(3,p3) LOADP(4,p4)
    LOADP(5,p5) LOADP(6,p6) LOADP(7,p7) LOADP(8,p8)

#pragma unroll
    for (int off = 1; off < 64; off <<= 1) nzmask |= __shfl_xor(nzmask, off, 64);
    if ((tid & 63) == 0) lds_or[tid >> 6] = nzmask;
    __syncthreads();

    int om = lds_or[0] | lds_or[1] | lds_or[2] | lds_or[3];

    // nontemporal: dst is streaming (35.4 MB, never re-read) -- keep `out` in L2
#define STOREP(C, V) { \
        float mk = ((om >> (C)) & 1) ? 1.0f : 0.0f; \
        V *= mk; \
        __builtin_nontemporal_store(V, (nf4*)(dst + (size_t)(C) * NWIN * 1024 + dbase)); }
    STOREP(0,p0) STOREP(1,p1) STOREP(2,p2) STOREP(3,p3) STOREP(4,p4)
    STOREP(5,p5) STOREP(6,p6) STOREP(7,p7) STOREP(8,p8)
}

extern "C" void kernel_launch(void* const* d_in, const int* in_sizes, int n_in,
                              void* d_out, int out_size, void* d_ws, size_t ws_size,
                              hipStream_t stream) {
    const float* img     = (const float*)d_in[0];
    const float* sigmas  = (const float*)d_in[1];
    const float* lambdas = (const float*)d_in[2];
    float* ws = (float*)d_ws;
    // ws layout (floats): partial[9*1024] @0, out @16384
    float* partial = ws;
    float* outb    = ws + 16384;   // 9*496*496 = 2,214,144 floats

    conv_kernel<<<dim3(NB, NB), 256, 0, stream>>>(img, sigmas, lambdas, outb, partial);
    patch_kernel<<<NWIN, 256, 0, stream>>>(outb, partial, (float*)d_out);
}

// Round 5
// 119.939 us; speedup vs baseline: 1.2472x; 1.2472x over previous
//
#include <hip/hip_runtime.h>
#include <math.h>

#define HH 496
#define WW 496
#define HWSZ (HH*WW)
#define NW 31
#define NWIN (NW*NW)   // 961
#define PARTSTRIDE 1024

typedef float nf4 __attribute__((ext_vector_type(4)));  // native vec for nontemporal builtin

__constant__ float c_thetas[8] = {
    0.39269908169872414f, 0.7853981633974483f, 1.1780972450961724f,
    1.5707963267948966f,  1.9634954084936207f, 2.356194490192345f,
    2.748893571891069f,   3.141592653589793f};

// ---- Kernel 1: Gabor bank TRANSPOSED as filt[k][f] (k=0..24, f=c*8+t) in GLOBAL ----
// Global + wave-uniform indices in conv => s_load into SGPRs (K$-resident, shared by
// all blocks). LDS broadcast reads were the round-2 bottleneck (~34us of ds_read issue).
__global__ void bank_kernel(const float* __restrict__ sigmas,
                            const float* __restrict__ lambdas,
                            float* __restrict__ filt) {
    int idx = threadIdx.x + blockIdx.x * blockDim.x;
    if (idx >= 1800) return;
    int f = idx / 25, k = idx % 25;
    int dy = k / 5, dx = k % 5;
    int s = f / 24, rem = f % 24, l = rem / 8, t = rem % 8;
    float sig = sigmas[s], lam = lambdas[l], th = c_thetas[t];
    float y = (float)dy - 2.0f, x = (float)dx - 2.0f;
    float st = sinf(th), ct = cosf(th);
    float yt = -x * st + y * ct;
    float xt =  x * ct + y * st;
    float sx2 = sig * sig;          // sigma_x = sig
    float sy2 = 4.0f * sig * sig;   // sigma_y = sig/0.5
    float g = expf(-0.5f * (xt * xt / sx2 + yt * yt / sy2)) *
              cosf(6.28318530717958647692f * xt / lam + 1.5707963267948966f);
    filt[k * 72 + f] = g;           // transposed layout
}

// named accumulators -- arrays get demoted to scratch (round-3 evidence: 96 accums
// -> VGPR=256 + 110MB scratch traffic; 24 accums + 25 px fits in ~80 VGPR)
#define FMAS(FP, P) \
    a0  = fmaf(P, (FP)[0],  a0);  a1  = fmaf(P, (FP)[1],  a1);  \
    a2  = fmaf(P, (FP)[2],  a2);  a3  = fmaf(P, (FP)[3],  a3);  \
    a4  = fmaf(P, (FP)[4],  a4);  a5  = fmaf(P, (FP)[5],  a5);  \
    a6  = fmaf(P, (FP)[6],  a6);  a7  = fmaf(P, (FP)[7],  a7);  \
    a8  = fmaf(P, (FP)[8],  a8);  a9  = fmaf(P, (FP)[9],  a9);  \
    a10 = fmaf(P, (FP)[10], a10); a11 = fmaf(P, (FP)[11], a11); \
    a12 = fmaf(P, (FP)[12], a12); a13 = fmaf(P, (FP)[13], a13); \
    a14 = fmaf(P, (FP)[14], a14); a15 = fmaf(P, (FP)[15], a15); \
    a16 = fmaf(P, (FP)[16], a16); a17 = fmaf(P, (FP)[17], a17); \
    a18 = fmaf(P, (FP)[18], a18); a19 = fmaf(P, (FP)[19], a19); \
    a20 = fmaf(P, (FP)[20], a20); a21 = fmaf(P, (FP)[21], a21); \
    a22 = fmaf(P, (FP)[22], a22); a23 = fmaf(P, (FP)[23], a23);

#define STEP(K) { const float* fp = fbase + (K)*72; FMAS(fp, p##K) }

#define ALLSTEPS \
    STEP(0)  STEP(1)  STEP(2)  STEP(3)  STEP(4)  \
    STEP(5)  STEP(6)  STEP(7)  STEP(8)  STEP(9)  \
    STEP(10) STEP(11) STEP(12) STEP(13) STEP(14) \
    STEP(15) STEP(16) STEP(17) STEP(18) STEP(19) \
    STEP(20) STEP(21) STEP(22) STEP(23) STEP(24)

#define RED(CC, MV) { \
        float s_ = MV; \
        s_ += __shfl_down(s_, 32, 64); s_ += __shfl_down(s_, 16, 64); \
        s_ += __shfl_down(s_,  8, 64); s_ += __shfl_down(s_,  4, 64); \
        s_ += __shfl_down(s_,  2, 64); s_ += __shfl_down(s_,  1, 64); \
        if ((tid & 63) == 0) red[tid >> 6][CC] = s_; }

// ---- Kernel 2: conv. 1 px/thread, all 3 channel groups per block (tile staged once).
// Filters via wave-uniform GLOBAL reads (s_load, K$). Per-block sums -> partial[]. ----
__global__ __launch_bounds__(256) void conv_kernel(
    const float* __restrict__ img, const float* __restrict__ filt,
    float* __restrict__ out, float* __restrict__ partial) {
    __shared__ float tile[20 * 20];
    __shared__ float red[4][9];
    int tid = threadIdx.x;
    int tx = tid & 15, ty = tid >> 4;
    int bx = blockIdx.x, by = blockIdx.y;

    for (int i = tid; i < 400; i += 256) {
        int tY = i / 20, tX = i % 20;
        int gy = by * 16 + tY - 2, gx = bx * 16 + tX - 2;
        float v = 0.0f;
        if (gy >= 0 && gy < HH && gx >= 0 && gx < WW) v = img[gy * WW + gx];
        tile[i] = v;
    }
    __syncthreads();

    int tbase = ty * 20 + tx;
    // hoist the 25 pixel loads into named registers (25 ds_read, shared by all cgs)
    float p0  = tile[tbase +  0], p1  = tile[tbase +  1], p2  = tile[tbase +  2],
          p3  = tile[tbase +  3], p4  = tile[tbase +  4];
    float p5  = tile[tbase + 20], p6  = tile[tbase + 21], p7  = tile[tbase + 22],
          p8  = tile[tbase + 23], p9  = tile[tbase + 24];
    float p10 = tile[tbase + 40], p11 = tile[tbase + 41], p12 = tile[tbase + 42],
          p13 = tile[tbase + 43], p14 = tile[tbase + 44];
    float p15 = tile[tbase + 60], p16 = tile[tbase + 61], p17 = tile[tbase + 62],
          p18 = tile[tbase + 63], p19 = tile[tbase + 64];
    float p20 = tile[tbase + 80], p21 = tile[tbase + 81], p22 = tile[tbase + 82],
          p23 = tile[tbase + 83], p24 = tile[tbase + 84];

    int y = by * 16 + ty, x = bx * 16 + tx;

#pragma unroll 1
    for (int cg = 0; cg < 3; ++cg) {
        const float* fbase = filt + cg * 24;
        float a0=0,a1=0,a2=0,a3=0,a4=0,a5=0,a6=0,a7=0,a8=0,a9=0,a10=0,a11=0,
              a12=0,a13=0,a14=0,a15=0,a16=0,a17=0,a18=0,a19=0,a20=0,a21=0,a22=0,a23=0;

        ALLSTEPS

        float m0 = fmaxf(fmaxf(fmaxf(a0,a1),fmaxf(a2,a3)),fmaxf(fmaxf(a4,a5),fmaxf(a6,a7)));
        float m1 = fmaxf(fmaxf(fmaxf(a8,a9),fmaxf(a10,a11)),fmaxf(fmaxf(a12,a13),fmaxf(a14,a15)));
        float m2 = fmaxf(fmaxf(fmaxf(a16,a17),fmaxf(a18,a19)),fmaxf(fmaxf(a20,a21),fmaxf(a22,a23)));

        out[(cg * 3 + 0) * HWSZ + y * WW + x] = m0;
        out[(cg * 3 + 1) * HWSZ + y * WW + x] = m1;
        out[(cg * 3 + 2) * HWSZ + y * WW + x] = m2;

        RED(cg * 3 + 0, m0)
        RED(cg * 3 + 1, m1)
        RED(cg * 3 + 2, m2)
    }

    __syncthreads();
    if (tid < 9) {
        int bid = by * NW + bx;
        partial[tid * PARTSTRIDE + bid] =
            red[0][tid] + red[1][tid] + red[2][tid] + red[3][tid];
    }
}

// ---- Kernel 3: mean-reduce preamble + per-window validity + patch copy (valid ~3.5%) ----
__global__ __launch_bounds__(256) void patch_kernel(
    const float* __restrict__ out, const float* __restrict__ partial,
    float* __restrict__ dst) {
    int w = blockIdx.x;
    int r = w / NW, cl = w % NW;
    int tid = threadIdx.x;
    __shared__ float sm5[9];
    __shared__ int lds_and[4];
    __shared__ int lds_or[4];

    // Preamble: reduce 961 per-block conv partials -> 5*mean per channel (all L2-hits)
    {
        int lane = tid & 63, wid = tid >> 6;
        for (int c = wid; c < 9; c += 4) {
            float s = 0.0f;
            for (int b = lane; b < NWIN; b += 64) s += partial[c * PARTSTRIDE + b];
            s += __shfl_down(s, 32, 64); s += __shfl_down(s, 16, 64);
            s += __shfl_down(s,  8, 64); s += __shfl_down(s,  4, 64);
            s += __shfl_down(s,  2, 64); s += __shfl_down(s,  1, 64);
            if (lane == 0) sm5[c] = s * (5.0f / (float)HWSZ);
        }
    }
    __syncthreads();

    // Stage 1: per-channel "argmax of thresholded window == 128" bit, AND over threads
    int wy = tid >> 4, wx = tid & 15;
    int rowbase = (r * 16 + wy) * WW + cl * 16 + wx;
    int cbase   = (r * 16 + 8) * WW + cl * 16;       // flat idx 128 = (8,0)
    int okmask = 0;
#pragma unroll
    for (int c = 0; c < 9; c++) {
        float m5 = sm5[c];
        float v  = out[c * HWSZ + rowbase];
        float vc = out[c * HWSZ + cbase];
        float thr  = (v  > m5) ? v  : 0.0f;
        float thrc = (vc > m5) ? vc : 0.0f;
        // first-occurrence argmax: earlier strictly less, later (incl. center) <=
        bool ok = (tid < 128) ? (thr < thrc) : (thr <= thrc);
        okmask |= (ok ? 1 : 0) << c;
    }
#pragma unroll
    for (int off = 1; off < 64; off <<= 1) okmask &= __shfl_xor(okmask, off, 64);
    if ((tid & 63) == 0) lds_and[tid >> 6] = okmask;
    __syncthreads();

    int am = lds_and[0] & lds_and[1] & lds_and[2] & lds_and[3];

    int i = tid >> 3;            // patch row 0..31
    int jg = (tid & 7) << 2;     // patch col group 0,4,...,28
    size_t dbase = (size_t)w * 1024 + i * 32 + jg;

    if (am == 0) {
        // no channel has center-argmax: entire 9-channel patch set is zero.
        // must still store (dst is poisoned), but skip all patch reads.
        nf4 z = (nf4){0.f, 0.f, 0.f, 0.f};
#pragma unroll
        for (int c = 0; c < 9; c++)
            __builtin_nontemporal_store(z, (nf4*)(dst + (size_t)c * NWIN * 1024 + dbase));
        return;
    }

    // Stage 2 (valid windows only): one float4 per (thread, channel); nz bitmask
    int row = r * 16 + i - 8;
    int col = cl * 16 + jg - 8;
    // 4-aligned col groups never straddle the [0,496) edge (496 % 4 == 0)
    bool inb = (row >= 0 && row < HH && col >= 0 && col + 3 < WW);
    size_t pbase = (size_t)row * WW + col;
    int nzmask = 0;
    nf4 p0, p1, p2, p3, p4, p5, p6, p7, p8;
#define LOADP(C, V) { \
        V = (nf4){0.f, 0.f, 0.f, 0.f}; \
        if (inb) V = *(const nf4*)(out + (size_t)(C) * HWSZ + pbase); \
        if (V.x != 0.f || V.y != 0.f || V.z != 0.f || V.w != 0.f) nzmask |= 1 << (C); }
    LOADP(0,p0) LOADP(1,p1) LOADP(2,p2) LOADP(3,p3) LOADP(4,p4)
    LOADP(5,p5) LOADP(6,p6) LOADP(7,p7) LOADP(8,p8)

#pragma unroll
    for (int off = 1; off < 64; off <<= 1) nzmask |= __shfl_xor(nzmask, off, 64);
    if ((tid & 63) == 0) lds_or[tid >> 6] = nzmask;
    __syncthreads();

    int om = lds_or[0] | lds_or[1] | lds_or[2] | lds_or[3];

    // nontemporal: dst is streaming (35.4 MB, never re-read) -- keep `out` in L2
#define STOREP(C, V) { \
        float mk = ((om >> (C)) & 1) ? 1.0f : 0.0f; \
        V *= mk; \
        __builtin_nontemporal_store(V, (nf4*)(dst + (size_t)(C) * NWIN * 1024 + dbase)); }
    STOREP(0,p0) STOREP(1,p1) STOREP(2,p2) STOREP(3,p3) STOREP(4,p4)
    STOREP(5,p5) STOREP(6,p6) STOREP(7,p7) STOREP(8,p8)
}

extern "C" void kernel_launch(void* const* d_in, const int* in_sizes, int n_in,
                              void* d_out, int out_size, void* d_ws, size_t ws_size,
                              hipStream_t stream) {
    const float* img     = (const float*)d_in[0];
    const float* sigmas  = (const float*)d_in[1];
    const float* lambdas = (const float*)d_in[2];
    float* ws = (float*)d_ws;
    // ws layout (floats): filt[1800] @0, partial[9*1024] @2048, out @16384
    float* filt    = ws;
    float* partial = ws + 2048;
    float* outb    = ws + 16384;   // 9*496*496 = 2,214,144 floats

    bank_kernel<<<8, 256, 0, stream>>>(sigmas, lambdas, filt);
    conv_kernel<<<dim3(NW, NW), 256, 0, stream>>>(img, filt, outb, partial);
    patch_kernel<<<NWIN, 256, 0, stream>>>(outb, partial, (float*)d_out);
}

// Round 7
// 118.313 us; speedup vs baseline: 1.2644x; 1.0137x over previous
//
#include <hip/hip_runtime.h>
#include <math.h>

#define HH 496
#define WW 496
#define HWSZ (HH*WW)
#define NW 31
#define NWIN (NW*NW)   // 961
#define PARTSTRIDE 1024

typedef float nf4 __attribute__((ext_vector_type(4)));  // native vec for nontemporal builtin

__constant__ float c_thetas[8] = {
    0.39269908169872414f, 0.7853981633974483f, 1.1780972450961724f,
    1.5707963267948966f,  1.9634954084936207f, 2.356194490192345f,
    2.748893571891069f,   3.141592653589793f};

// filters read from LDS (flds), wave-uniform address = broadcast; offsets are
// compile-time constants (byte offset = 96*(3K+CG)+4N, 16B-aligned groups)
#define FMAS(B, P) \
    a0  = fmaf(P, flds[(B)+0],  a0);  a1  = fmaf(P, flds[(B)+1],  a1);  \
    a2  = fmaf(P, flds[(B)+2],  a2);  a3  = fmaf(P, flds[(B)+3],  a3);  \
    a4  = fmaf(P, flds[(B)+4],  a4);  a5  = fmaf(P, flds[(B)+5],  a5);  \
    a6  = fmaf(P, flds[(B)+6],  a6);  a7  = fmaf(P, flds[(B)+7],  a7);  \
    a8  = fmaf(P, flds[(B)+8],  a8);  a9  = fmaf(P, flds[(B)+9],  a9);  \
    a10 = fmaf(P, flds[(B)+10], a10); a11 = fmaf(P, flds[(B)+11], a11); \
    a12 = fmaf(P, flds[(B)+12], a12); a13 = fmaf(P, flds[(B)+13], a13); \
    a14 = fmaf(P, flds[(B)+14], a14); a15 = fmaf(P, flds[(B)+15], a15); \
    a16 = fmaf(P, flds[(B)+16], a16); a17 = fmaf(P, flds[(B)+17], a17); \
    a18 = fmaf(P, flds[(B)+18], a18); a19 = fmaf(P, flds[(B)+19], a19); \
    a20 = fmaf(P, flds[(B)+20], a20); a21 = fmaf(P, flds[(B)+21], a21); \
    a22 = fmaf(P, flds[(B)+22], a22); a23 = fmaf(P, flds[(B)+23], a23);

#define STEP(K, CG) { FMAS((K)*72 + (CG)*24, p##K) }

#define ALLSTEPS(CG) \
    STEP(0,CG)  STEP(1,CG)  STEP(2,CG)  STEP(3,CG)  STEP(4,CG)  \
    STEP(5,CG)  STEP(6,CG)  STEP(7,CG)  STEP(8,CG)  STEP(9,CG)  \
    STEP(10,CG) STEP(11,CG) STEP(12,CG) STEP(13,CG) STEP(14,CG) \
    STEP(15,CG) STEP(16,CG) STEP(17,CG) STEP(18,CG) STEP(19,CG) \
    STEP(20,CG) STEP(21,CG) STEP(22,CG) STEP(23,CG) STEP(24,CG)

#define RED(CC, MV) { \
        float s_ = MV; \
        s_ += __shfl_down(s_, 32, 64); s_ += __shfl_down(s_, 16, 64); \
        s_ += __shfl_down(s_,  8, 64); s_ += __shfl_down(s_,  4, 64); \
        s_ += __shfl_down(s_,  2, 64); s_ += __shfl_down(s_,  1, 64); \
        if ((tid & 63) == 0) red[tid >> 6][CC] = s_; }

// one channel group = 24 filters; accumulators live only inside this scope
#define CONVCG(CG) { \
        float a0=0,a1=0,a2=0,a3=0,a4=0,a5=0,a6=0,a7=0,a8=0,a9=0,a10=0,a11=0, \
              a12=0,a13=0,a14=0,a15=0,a16=0,a17=0,a18=0,a19=0,a20=0,a21=0,a22=0,a23=0; \
        ALLSTEPS(CG) \
        float m0 = fmaxf(fmaxf(fmaxf(a0,a1),fmaxf(a2,a3)),fmaxf(fmaxf(a4,a5),fmaxf(a6,a7))); \
        float m1 = fmaxf(fmaxf(fmaxf(a8,a9),fmaxf(a10,a11)),fmaxf(fmaxf(a12,a13),fmaxf(a14,a15))); \
        float m2 = fmaxf(fmaxf(fmaxf(a16,a17),fmaxf(a18,a19)),fmaxf(fmaxf(a20,a21),fmaxf(a22,a23))); \
        out[((CG) * 3 + 0) * HWSZ + y * WW + x] = m0; \
        out[((CG) * 3 + 1) * HWSZ + y * WW + x] = m1; \
        out[((CG) * 3 + 2) * HWSZ + y * WW + x] = m2; \
        RED((CG) * 3 + 0, m0) RED((CG) * 3 + 1, m1) RED((CG) * 3 + 2, m2) \
    }

// ---- Kernel 1: fused bank+conv. Each block computes the 1800-float Gabor bank into
// LDS (~7 transcendental iters/thread, hidden under the tile-stage HBM latency), then
// convolves its 16x16 tile for all 9 channels. Per-block sums go to partial[]. ----
__global__ __launch_bounds__(256) void conv_kernel(
    const float* __restrict__ img,
    const float* __restrict__ sigmas, const float* __restrict__ lambdas,
    float* __restrict__ out, float* __restrict__ partial) {
    __shared__ float tile[20 * 20];
    __shared__ __align__(16) float flds[1800];
    __shared__ float red[4][9];
    int tid = threadIdx.x;
    int tx = tid & 15, ty = tid >> 4;
    int bx = blockIdx.x, by = blockIdx.y;

    // stage image tile (global loads issue first; filter math below overlaps the latency)
    for (int i = tid; i < 400; i += 256) {
        int tY = i / 20, tX = i % 20;
        int gy = by * 16 + tY - 2, gx = bx * 16 + tX - 2;
        float v = 0.0f;
        if (gy >= 0 && gy < HH && gx >= 0 && gx < WW) v = img[gy * WW + gx];
        tile[i] = v;
    }
    // compute Gabor bank into LDS -- bit-identical math to the original bank_kernel
    for (int idx = tid; idx < 1800; idx += 256) {
        int f = idx / 25, k = idx % 25;
        int dy = k / 5, dx = k % 5;
        int s = f / 24, rem = f % 24, l = rem / 8, t = rem % 8;
        float sig = sigmas[s], lam = lambdas[l], th = c_thetas[t];
        float yy = (float)dy - 2.0f, xx = (float)dx - 2.0f;
        float st = sinf(th), ct = cosf(th);
        float yt = -xx * st + yy * ct;
        float xt =  xx * ct + yy * st;
        float sx2 = sig * sig;          // sigma_x = sig
        float sy2 = 4.0f * sig * sig;   // sigma_y = sig/0.5
        float g = expf(-0.5f * (xt * xt / sx2 + yt * yt / sy2)) *
                  cosf(6.28318530717958647692f * xt / lam + 1.5707963267948966f);
        flds[k * 72 + f] = g;           // transposed layout: filt[k][f]
    }
    __syncthreads();

    int tbase = ty * 20 + tx;
    // hoist the 25 pixel loads into named registers (exactly 25 ds_read_b32, shared by all cgs)
    float p0  = tile[tbase +  0], p1  = tile[tbase +  1], p2  = tile[tbase +  2],
          p3  = tile[tbase +  3], p4  = tile[tbase +  4];
    float p5  = tile[tbase + 20], p6  = tile[tbase + 21], p7  = tile[tbase + 22],
          p8  = tile[tbase + 23], p9  = tile[tbase + 24];
    float p10 = tile[tbase + 40], p11 = tile[tbase + 41], p12 = tile[tbase + 42],
          p13 = tile[tbase + 43], p14 = tile[tbase + 44];
    float p15 = tile[tbase + 60], p16 = tile[tbase + 61], p17 = tile[tbase + 62],
          p18 = tile[tbase + 63], p19 = tile[tbase + 64];
    float p20 = tile[tbase + 80], p21 = tile[tbase + 81], p22 = tile[tbase + 82],
          p23 = tile[tbase + 83], p24 = tile[tbase + 84];

    int y = by * 16 + ty, x = bx * 16 + tx;

    CONVCG(0)
    CONVCG(1)
    CONVCG(2)

    __syncthreads();
    if (tid < 9) {
        int bid = by * NW + bx;
        partial[tid * PARTSTRIDE + bid] =
            red[0][tid] + red[1][tid] + red[2][tid] + red[3][tid];
    }
}

// ---- Kernel 2: mean-reduce preamble + per-window validity + patch copy (valid ~3.5%) ----
__global__ __launch_bounds__(256) void patch_kernel(
    const float* __restrict__ out, const float* __restrict__ partial,
    float* __restrict__ dst) {
    int w = blockIdx.x;
    int r = w / NW, cl = w % NW;
    int tid = threadIdx.x;
    __shared__ float sm5[9];
    __shared__ int lds_and[4];
    __shared__ int lds_or[4];

    // Preamble: reduce per-block conv partials -> 5*mean per channel (all L2-hits)
    {
        int lane = tid & 63, wid = tid >> 6;
        for (int c = wid; c < 9; c += 4) {
            float s = 0.0f;
            for (int b = lane; b < NWIN; b += 64) s += partial[c * PARTSTRIDE + b];
            s += __shfl_down(s, 32, 64); s += __shfl_down(s, 16, 64);
            s += __shfl_down(s,  8, 64); s += __shfl_down(s,  4, 64);
            s += __shfl_down(s,  2, 64); s += __shfl_down(s,  1, 64);
            if (lane == 0) sm5[c] = s * (5.0f / (float)HWSZ);
        }
    }
    __syncthreads();

    // Stage 1: per-channel "argmax of thresholded window == 128" bit, AND over threads
    int wy = tid >> 4, wx = tid & 15;
    int rowbase = (r * 16 + wy) * WW + cl * 16 + wx;
    int cbase   = (r * 16 + 8) * WW + cl * 16;       // flat idx 128 = (8,0)
    int okmask = 0;
#pragma unroll
    for (int c = 0; c < 9; c++) {
        float m5 = sm5[c];
        float v  = out[c * HWSZ + rowbase];
        float vc = out[c * HWSZ + cbase];
        float thr  = (v  > m5) ? v  : 0.0f;
        float thrc = (vc > m5) ? vc : 0.0f;
        // first-occurrence argmax: earlier strictly less, later (incl. center) <=
        bool ok = (tid < 128) ? (thr < thrc) : (thr <= thrc);
        okmask |= (ok ? 1 : 0) << c;
    }
#pragma unroll
    for (int off = 1; off < 64; off <<= 1) okmask &= __shfl_xor(okmask, off, 64);
    if ((tid & 63) == 0) lds_and[tid >> 6] = okmask;
    __syncthreads();

    int am = lds_and[0] & lds_and[1] & lds_and[2] & lds_and[3];

    int i = tid >> 3;            // patch row 0..31
    int jg = (tid & 7) << 2;     // patch col group 0,4,...,28
    size_t dbase = (size_t)w * 1024 + i * 32 + jg;

    if (am == 0) {
        // no channel has center-argmax: entire 9-channel patch set is zero.
        // must still store (dst is poisoned), but skip all patch reads.
        nf4 z = (nf4){0.f, 0.f, 0.f, 0.f};
#pragma unroll
        for (int c = 0; c < 9; c++)
            __builtin_nontemporal_store(z, (nf4*)(dst + (size_t)c * NWIN * 1024 + dbase));
        return;
    }

    // Stage 2 (valid windows only): one float4 per (thread, channel); nz bitmask
    int row = r * 16 + i - 8;
    int col = cl * 16 + jg - 8;
    // 4-aligned col groups never straddle the [0,496) edge (496 % 4 == 0)
    bool inb = (row >= 0 && row < HH && col >= 0 && col + 3 < WW);
    size_t pbase = (size_t)row * WW + col;
    int nzmask = 0;
    nf4 p0, p1, p2, p3, p4, p5, p6, p7, p8;
#define LOADP(C, V) { \
        V = (nf4){0.f, 0.f, 0.f, 0.f}; \
        if (inb) V = *(const nf4*)(out + (size_t)(C) * HWSZ + pbase); \
        if (V.x != 0.f || V.y != 0.f || V.z != 0.f || V.w != 0.f) nzmask |= 1 << (C); }
    LOADP(0,p0) LOADP(1,p1) LOADP(2,p2) LOADP(3,p3) LOADP(4,p4)
    LOADP(5,p5) LOADP(6,p6) LOADP(7,p7) LOADP(8,p8)

#pragma unroll
    for (int off = 1; off < 64; off <<= 1) nzmask |= __shfl_xor(nzmask, off, 64);
    if ((tid & 63) == 0) lds_or[tid >> 6] = nzmask;
    __syncthreads();

    int om = lds_or[0] | lds_or[1] | lds_or[2] | lds_or[3];

    // nontemporal: dst is streaming (35.4 MB, never re-read) -- keep `out` in L2
#define STOREP(C, V) { \
        float mk = ((om >> (C)) & 1) ? 1.0f : 0.0f; \
        V *= mk; \
        __builtin_nontemporal_store(V, (nf4*)(dst + (size_t)(C) * NWIN * 1024 + dbase)); }
    STOREP(0,p0) STOREP(1,p1) STOREP(2,p2) STOREP(3,p3) STOREP(4,p4)
    STOREP(5,p5) STOREP(6,p6) STOREP(7,p7) STOREP(8,p8)
}

extern "C" void kernel_launch(void* const* d_in, const int* in_sizes, int n_in,
                              void* d_out, int out_size, void* d_ws, size_t ws_size,
                              hipStream_t stream) {
    const float* img     = (const float*)d_in[0];
    const float* sigmas  = (const float*)d_in[1];
    const float* lambdas = (const float*)d_in[2];
    float* ws = (float*)d_ws;
    // ws layout (floats): partial[9*1024] @0, out @16384
    float* partial = ws;
    float* outb    = ws + 16384;   // 9*496*496 = 2,214,144 floats

    conv_kernel<<<dim3(NW, NW), 256, 0, stream>>>(img, sigmas, lambdas, outb, partial);
    patch_kernel<<<NWIN, 256, 0, stream>>>(outb, partial, (float*)d_out);
}